// Round 1
// baseline (126.722 us; speedup 1.0000x reference)
//
#include <hip/hip_runtime.h>

#define NROWS 8192
#define INF_NEG -9000000000000000.0f
#define NSPLIT 8
#define JT (NROWS / NSPLIT)  // 1024 j's per split

typedef __attribute__((ext_vector_type(4))) float f32x4;
typedef __attribute__((ext_vector_type(8))) __bf16 bf16x8;
typedef __attribute__((ext_vector_type(8))) unsigned short ushort8;

__device__ __forceinline__ unsigned short f2bf(float x) {
  unsigned u = __float_as_uint(x);
  u += 0x7fffu + ((u >> 16) & 1u);
  return (unsigned short)(u >> 16);
}

// ---------------------------------------------------------------------------
// Kernel A: Wh = h@W (stored bf16 in MFMA-B-fragment order), src=Wh@a1, dst=Wh@a2
// One wave per row; lane = output feature (64 features = 64 lanes).
// Fragment layout: slot (jc, nt, lane, e) holds Wh[j = 32*jc + 8*(lane>>4) + e][nt*16 + (lane&15)]
// ---------------------------------------------------------------------------
__global__ __launch_bounds__(256) void k_prep(
    const float* __restrict__ h, const float* __restrict__ W,
    const float* __restrict__ a, unsigned short* __restrict__ WhB,
    float* __restrict__ src, float* __restrict__ dst) {
  int i = blockIdx.x * 4 + (threadIdx.x >> 6);  // row
  int lane = threadIdx.x & 63;                  // feature
  const float* hrow = h + (size_t)i * 256;
  float s = 0.f;
#pragma unroll 4
  for (int k = 0; k < 256; k += 4) {
    float4 hv = *(const float4*)(hrow + k);
    s = fmaf(hv.x, W[(k + 0) * 64 + lane], s);
    s = fmaf(hv.y, W[(k + 1) * 64 + lane], s);
    s = fmaf(hv.z, W[(k + 2) * 64 + lane], s);
    s = fmaf(hv.w, W[(k + 3) * 64 + lane], s);
  }
  // scatter into B-fragment layout (j = i here)
  int nt = lane >> 4, c = lane & 15;
  int gi = (i >> 3) & 3, e = i & 7;
  int idx = ((((i >> 5) * 4 + nt) * 64) + c + 16 * gi) * 8 + e;
  WhB[idx] = f2bf(s);
  // src/dst reductions
  float v1 = s * a[lane];
  float v2 = s * a[64 + lane];
#pragma unroll
  for (int d = 32; d; d >>= 1) {
    v1 += __shfl_xor(v1, d);
    v2 += __shfl_xor(v2, d);
  }
  if (lane == 0) {
    src[i] = v1;
    dst[i] = v2;
  }
}

// ---------------------------------------------------------------------------
// Kernel B: fused masked-softmax + PV, split along j into NSPLIT partials.
// One wave = one (16-row M-tile, split) task. Online softmax per row.
// ---------------------------------------------------------------------------
__global__ __launch_bounds__(256) void k_attn(
    const int* __restrict__ adj, const unsigned short* __restrict__ WhB,
    const float* __restrict__ src, const float* __restrict__ dst,
    float* __restrict__ pm, float* __restrict__ pl, float* __restrict__ pacc) {
  int task = blockIdx.x * 4 + (threadIdx.x >> 6);  // 0 .. 512*NSPLIT-1
  int sp = task >> 9;                              // split index
  int mt = task & 511;                             // M-tile index
  int lane = threadIdx.x & 63;
  int r = lane & 15;   // A-operand row within tile / C col
  int g = lane >> 4;   // k-slot group
  int row0 = mt * 16;
  float srcr = src[row0 + r];
  float m = -INFINITY;
  float lrow = 0.f;
  f32x4 acc[4] = {f32x4{0.f, 0.f, 0.f, 0.f}, f32x4{0.f, 0.f, 0.f, 0.f},
                  f32x4{0.f, 0.f, 0.f, 0.f}, f32x4{0.f, 0.f, 0.f, 0.f}};
  int jbase = sp * JT;
  const int* adjp = adj + (size_t)(row0 + r) * NROWS + jbase + 8 * g;
  const float* dstp = dst + jbase + 8 * g;
  const bf16x8* Bfr = (const bf16x8*)WhB;

  for (int jb = 0; jb < JT; jb += 64) {
    int4 a0 = *(const int4*)(adjp + jb);
    int4 a1 = *(const int4*)(adjp + jb + 4);
    int4 a2 = *(const int4*)(adjp + jb + 32);
    int4 a3 = *(const int4*)(adjp + jb + 36);
    float4 d0 = *(const float4*)(dstp + jb);
    float4 d1 = *(const float4*)(dstp + jb + 4);
    float4 d2 = *(const float4*)(dstp + jb + 32);
    float4 d3 = *(const float4*)(dstp + jb + 36);

    float ev[16];
#define EC(aa, dd)                        \
  ({                                      \
    float v_ = srcr + (dd);               \
    v_ = fmaxf(v_, 0.2f * v_);            \
    ((aa) > 0) ? v_ : INF_NEG;            \
  })
    ev[0] = EC(a0.x, d0.x);  ev[1] = EC(a0.y, d0.y);
    ev[2] = EC(a0.z, d0.z);  ev[3] = EC(a0.w, d0.w);
    ev[4] = EC(a1.x, d1.x);  ev[5] = EC(a1.y, d1.y);
    ev[6] = EC(a1.z, d1.z);  ev[7] = EC(a1.w, d1.w);
    ev[8] = EC(a2.x, d2.x);  ev[9] = EC(a2.y, d2.y);
    ev[10] = EC(a2.z, d2.z); ev[11] = EC(a2.w, d2.w);
    ev[12] = EC(a3.x, d3.x); ev[13] = EC(a3.y, d3.y);
    ev[14] = EC(a3.z, d3.z); ev[15] = EC(a3.w, d3.w);
#undef EC

    float cm = ev[0];
#pragma unroll
    for (int t = 1; t < 16; t++) cm = fmaxf(cm, ev[t]);
    cm = fmaxf(cm, __shfl_xor(cm, 16));
    cm = fmaxf(cm, __shfl_xor(cm, 32));
    float mnew = fmaxf(m, cm);

    float pv[16];
    float ps = 0.f;
#pragma unroll
    for (int t = 0; t < 16; t++) {
      pv[t] = __expf(ev[t] - mnew);
      ps += pv[t];
    }
    ps += __shfl_xor(ps, 16);
    ps += __shfl_xor(ps, 32);

    if (__any(mnew > m)) {
      float sc = __expf(m - mnew);  // this lane's row (r) scale
      float s0 = __shfl(sc, 4 * g + 0);
      float s1 = __shfl(sc, 4 * g + 1);
      float s2 = __shfl(sc, 4 * g + 2);
      float s3 = __shfl(sc, 4 * g + 3);
#pragma unroll
      for (int nt = 0; nt < 4; nt++) {
        acc[nt][0] *= s0;
        acc[nt][1] *= s1;
        acc[nt][2] *= s2;
        acc[nt][3] *= s3;
      }
      lrow = lrow * sc + ps;
    } else {
      lrow += ps;
    }
    m = mnew;

    ushort8 u0, u1;
#pragma unroll
    for (int e = 0; e < 8; e++) {
      u0[e] = f2bf(pv[e]);
      u1[e] = f2bf(pv[8 + e]);
    }
    bf16x8 A0 = __builtin_bit_cast(bf16x8, u0);
    bf16x8 A1 = __builtin_bit_cast(bf16x8, u1);
    int jc = (jbase + jb) >> 5;
#pragma unroll
    for (int nt = 0; nt < 4; nt++) {
      bf16x8 B0 = Bfr[((jc) * 4 + nt) * 64 + lane];
      bf16x8 B1 = Bfr[((jc + 1) * 4 + nt) * 64 + lane];
      acc[nt] = __builtin_amdgcn_mfma_f32_16x16x32_bf16(A0, B0, acc[nt], 0, 0, 0);
      acc[nt] = __builtin_amdgcn_mfma_f32_16x16x32_bf16(A1, B1, acc[nt], 0, 0, 0);
    }
  }

  if (lane < 16) {
    pm[sp * NROWS + row0 + lane] = m;
    pl[sp * NROWS + row0 + lane] = lrow;
  }
#pragma unroll
  for (int nt = 0; nt < 4; nt++)
#pragma unroll
    for (int q = 0; q < 4; q++)
      pacc[((size_t)sp * NROWS + row0 + 4 * g + q) * 64 + nt * 16 + r] = acc[nt][q];
}

// ---------------------------------------------------------------------------
// Kernel C: combine split partials. One thread per output element.
// ---------------------------------------------------------------------------
__global__ __launch_bounds__(256) void k_comb(
    const float* __restrict__ pm, const float* __restrict__ pl,
    const float* __restrict__ pacc, float* __restrict__ out) {
  int t = blockIdx.x * 256 + threadIdx.x;
  int row = t >> 6, f = t & 63;
  float mv[NSPLIT];
  float M = -INFINITY;
#pragma unroll
  for (int s2 = 0; s2 < NSPLIT; s2++) {
    mv[s2] = pm[s2 * NROWS + row];
    M = fmaxf(M, mv[s2]);
  }
  float L = 0.f, o = 0.f;
#pragma unroll
  for (int s2 = 0; s2 < NSPLIT; s2++) {
    float w = __expf(mv[s2] - M);
    L += pl[s2 * NROWS + row] * w;
    o += pacc[((size_t)s2 * NROWS + row) * 64 + f] * w;
  }
  out[t] = o / L;
}

extern "C" void kernel_launch(void* const* d_in, const int* in_sizes, int n_in,
                              void* d_out, int out_size, void* d_ws, size_t ws_size,
                              hipStream_t stream) {
  const float* h = (const float*)d_in[0];
  const float* W = (const float*)d_in[1];
  const float* a = (const float*)d_in[2];
  const int* adj = (const int*)d_in[3];
  float* out = (float*)d_out;

  char* ws = (char*)d_ws;
  unsigned short* WhB = (unsigned short*)ws;                     // 1 MB
  float* src = (float*)(ws + (1 << 20));                         // 32 KB
  float* dst = (float*)(ws + (1 << 20) + 32768);                 // 32 KB
  float* pm = (float*)(ws + (1 << 20) + 65536);                  // 256 KB
  float* pl = (float*)(ws + (1 << 20) + 65536 + NSPLIT * NROWS * 4);
  float* pacc = (float*)(ws + (1 << 20) + 65536 + 2 * NSPLIT * NROWS * 4);  // 16 MB

  hipLaunchKernelGGL(k_prep, dim3(NROWS / 4), dim3(256), 0, stream, h, W, a, WhB, src, dst);
  hipLaunchKernelGGL(k_attn, dim3(512 * NSPLIT / 4), dim3(256), 0, stream,
                     adj, WhB, src, dst, pm, pl, pacc);
  hipLaunchKernelGGL(k_comb, dim3(NROWS * 64 / 256), dim3(256), 0, stream, pm, pl, pacc, out);
}